// Round 3
// baseline (1446.828 us; speedup 1.0000x reference)
//
#include <hip/hip_runtime.h>
#include <stdint.h>

// Fused Swin-V2 window attention (fp32 I/O, bf16 MFMA compute).
// One block per window (1024 blocks, 9 waves of 64).
// d_ws: [rbias fp32 663KB][qkv_w bf16 393KB][proj_w bf16 131KB] = 1.13 MB.

typedef __attribute__((ext_vector_type(4))) float floatx4;
typedef __attribute__((ext_vector_type(8))) __bf16 bf16x8;

__device__ __forceinline__ uint16_t f2bf(float f) {
    union { float f32; uint32_t u; } x;
    x.f32 = f;
    uint32_t r = x.u + 0x7FFFu + ((x.u >> 16) & 1u);  // RNE
    return (uint16_t)(r >> 16);
}

// load 8 consecutive fp32 -> bf16x8 fragment (16B-aligned source)
__device__ __forceinline__ bf16x8 cvt8(const float* __restrict__ p) {
    const floatx4 a = *(const floatx4*)p;
    const floatx4 b = *(const floatx4*)(p + 4);
    union { bf16x8 v; uint16_t u[8]; } r;
    r.u[0] = f2bf(a[0]); r.u[1] = f2bf(a[1]); r.u[2] = f2bf(a[2]); r.u[3] = f2bf(a[3]);
    r.u[4] = f2bf(b[0]); r.u[5] = f2bf(b[1]); r.u[6] = f2bf(b[2]); r.u[7] = f2bf(b[3]);
    return r.v;
}

// ---------------------------------------------------------------------------
// prep: convert qkv_w (768x256) and proj_w (256x256) fp32 -> bf16 in ws
// ---------------------------------------------------------------------------
__global__ __launch_bounds__(256) void cvtw_kernel(const float* __restrict__ qkvw,
                                                   const float* __restrict__ projw,
                                                   uint16_t* __restrict__ wqkv,
                                                   uint16_t* __restrict__ wproj) {
    const int i = blockIdx.x * 256 + threadIdx.x;
    if (i < 768 * 256) wqkv[i] = f2bf(qkvw[i]);
    if (i < 256 * 256) wproj[i] = f2bf(projw[i]);
}

// ---------------------------------------------------------------------------
// Relative-position bias via meta MLP: outb[h][p], p = i*144 + j, fp32.
// ---------------------------------------------------------------------------
__global__ __launch_bounds__(256) void rbias_kernel(const float* __restrict__ fc1w,
                                                    const float* __restrict__ fc1b,
                                                    const float* __restrict__ fc2w,
                                                    const float* __restrict__ fc2b,
                                                    float* __restrict__ outb) {
    __shared__ float w1a[384], w1b[384], b1[384];
    __shared__ float w2[8 * 384];
    for (int i = threadIdx.x; i < 384; i += 256) {
        w1a[i] = fc1w[2 * i];
        w1b[i] = fc1w[2 * i + 1];
        b1[i]  = fc1b[i];
    }
    for (int i = threadIdx.x; i < 3072; i += 256) w2[i] = fc2w[i];
    __syncthreads();
    const int p = blockIdx.x * 256 + threadIdx.x;
    if (p >= 144 * 144) return;
    const int i = p / 144;
    const int j = p - i * 144;
    const float dy = (float)(i / 12 - j / 12);
    const float dx = (float)(i % 12 - j % 12);
    const float cy = (dy > 0.f ? 1.f : (dy < 0.f ? -1.f : 0.f)) * log1pf(fabsf(dy));
    const float cx = (dx > 0.f ? 1.f : (dx < 0.f ? -1.f : 0.f)) * log1pf(fabsf(dx));
    float acc[8] = {0, 0, 0, 0, 0, 0, 0, 0};
    for (int t = 0; t < 384; t++) {
        float hv = fmaf(cy, w1a[t], fmaf(cx, w1b[t], b1[t]));
        hv = fmaxf(hv, 0.f);
#pragma unroll
        for (int hh = 0; hh < 8; hh++) acc[hh] = fmaf(hv, w2[hh * 384 + t], acc[hh]);
    }
#pragma unroll
    for (int hh = 0; hh < 8; hh++) outb[(size_t)hh * 20736 + p] = acc[hh] + fc2b[hh];
}

// ---------------------------------------------------------------------------
// Fused kernel: per window b -- for each head: qkv gemm (K=256, MFMA),
// cosine-normalize, S=qn@kn^T*scale + rbias + mask, softmax, P@V, proj partial
// (K=32 per head) accumulated into 16 fp32x4 tiles, fp32 epilogue.
// LDS (uint16): vT[0,5120) | qn[5120,9728) kn[9728,14336) | P[5120,28160) | OB[5120,9728)
// ---------------------------------------------------------------------------
__global__ __launch_bounds__(576, 2) void fused_kernel(const float* __restrict__ x,
                                                       const float* __restrict__ mask,
                                                       const uint16_t* __restrict__ qkvw,
                                                       const float* __restrict__ qkvb,
                                                       const uint16_t* __restrict__ projw,
                                                       const float* __restrict__ projb,
                                                       const float* __restrict__ rbias,
                                                       const float* __restrict__ lsc,
                                                       float* __restrict__ out) {
    __shared__ __align__(16) uint16_t sm[28160];  // 56.3 KB
    uint16_t* const vT = sm;          // [32][160], cols 144..159 zero
    uint16_t* const qn = sm + 5120;   // [144][32]
    uint16_t* const kn = sm + 9728;   // [144][32]
    uint16_t* const PB = sm + 5120;   // [144][160]
    uint16_t* const OB = sm + 5120;   // [144][32]

    const int b    = blockIdx.x;
    const int tid  = threadIdx.x;
    const int lane = tid & 63;
    const int mi   = tid >> 6;          // band 0..8 (16 rows each)
    const int lr   = lane & 15;
    const int kq   = (lane >> 4) << 3;  // A/B-frag k offset (quad*8)
    const int rq   = (lane >> 4) << 2;  // C-layout row offset (quad*4)
    const int arow = mi * 16 + lr;      // A-frag row for this lane

    if (tid < 512) vT[(tid >> 4) * 160 + 144 + (tid & 15)] = 0;  // zero pad cols once

    const float* xg = x + (size_t)b * 144 * 256;
    const float* mw = mask + (size_t)(b & 63) * 20736;

    floatx4 oacc[16];
#pragma unroll
    for (int i = 0; i < 16; i++) oacc[i] = (floatx4){0.f, 0.f, 0.f, 0.f};

#pragma unroll 1
    for (int h = 0; h < 8; ++h) {
        // ---- QKV gemm for head h: acc = {q0,q1,k0,k1,v0,v1} 16x16 tiles ----
        floatx4 acc[6];
#pragma unroll
        for (int t = 0; t < 6; t++) acc[t] = (floatx4){0.f, 0.f, 0.f, 0.f};
#pragma unroll 1
        for (int k = 0; k < 8; ++k) {
            const bf16x8 af = cvt8(xg + arow * 256 + k * 32 + kq);
#pragma unroll
            for (int t = 0; t < 6; t++) {
                const int wrow = (t >> 1) * 256 + h * 32 + (t & 1) * 16 + lr;
                const bf16x8 bfr = *(const bf16x8*)(qkvw + (size_t)wrow * 256 + k * 32 + kq);
                acc[t] = __builtin_amdgcn_mfma_f32_16x16x32_bf16(af, bfr, acc[t], 0, 0, 0);
            }
        }
#pragma unroll
        for (int t = 0; t < 6; t++) {
            const float bb = qkvb[(t >> 1) * 256 + h * 32 + (t & 1) * 16 + lr];
#pragma unroll
            for (int r = 0; r < 4; r++) acc[t][r] += bb;
        }
        // ---- cosine-normalize q,k rows (C-layout, 16-lane reduce) ----
#pragma unroll
        for (int r = 0; r < 4; r++) {
            const int row = mi * 16 + rq + r;
            float sq = acc[0][r] * acc[0][r] + acc[1][r] * acc[1][r];
            float sk = acc[2][r] * acc[2][r] + acc[3][r] * acc[3][r];
#pragma unroll
            for (int o = 1; o < 16; o <<= 1) {
                sq += __shfl_xor(sq, o, 64);
                sk += __shfl_xor(sk, o, 64);
            }
            const float rnq = 1.0f / fmaxf(sqrtf(sq), 1e-12f);
            const float rnk = 1.0f / fmaxf(sqrtf(sk), 1e-12f);
            qn[row * 32 + lr]      = f2bf(acc[0][r] * rnq);
            qn[row * 32 + 16 + lr] = f2bf(acc[1][r] * rnq);
            kn[row * 32 + lr]      = f2bf(acc[2][r] * rnk);
            kn[row * 32 + 16 + lr] = f2bf(acc[3][r] * rnk);
            vT[lr * 160 + row]        = f2bf(acc[4][r]);
            vT[(16 + lr) * 160 + row] = f2bf(acc[5][r]);
        }
        __syncthreads();  // S1: qn/kn/vT ready

        // ---- S = qn @ kn^T * scale + rbias + mask ----
        const float scale = __expf(fminf(lsc[h], 4.6051701859880914f));
        const float* bh = rbias + (size_t)h * 20736;
        const bf16x8 aq = *(const bf16x8*)&qn[arow * 32 + kq];
        float sl[9][4];
#pragma unroll
        for (int ni = 0; ni < 9; ni++) {
            const bf16x8 bk = *(const bf16x8*)&kn[(ni * 16 + lr) * 32 + kq];
            floatx4 s = (floatx4){0.f, 0.f, 0.f, 0.f};
            s = __builtin_amdgcn_mfma_f32_16x16x32_bf16(aq, bk, s, 0, 0, 0);
#pragma unroll
            for (int r = 0; r < 4; r++) {
                const int row = mi * 16 + rq + r;
                const int col = ni * 16 + lr;
                sl[ni][r] = s[r] * scale + bh[row * 144 + col] + mw[row * 144 + col];
            }
        }
        // ---- softmax over 144 cols ----
#pragma unroll
        for (int r = 0; r < 4; r++) {
            float m = -3.0e38f;
#pragma unroll
            for (int ni = 0; ni < 9; ni++) m = fmaxf(m, sl[ni][r]);
#pragma unroll
            for (int o = 1; o < 16; o <<= 1) m = fmaxf(m, __shfl_xor(m, o, 64));
            float s = 0.f;
#pragma unroll
            for (int ni = 0; ni < 9; ni++) {
                float e = __expf(sl[ni][r] - m);
                sl[ni][r] = e;
                s += e;
            }
#pragma unroll
            for (int o = 1; o < 16; o <<= 1) s += __shfl_xor(s, o, 64);
            const float inv = 1.0f / s;
#pragma unroll
            for (int ni = 0; ni < 9; ni++) sl[ni][r] *= inv;
        }
        __syncthreads();  // S2: qn/kn reads done before P overlays them

        // ---- P -> LDS row-major [144][160], pad cols zeroed ----
#pragma unroll
        for (int ni = 0; ni < 9; ni++)
#pragma unroll
            for (int r = 0; r < 4; r++)
                PB[(mi * 16 + rq + r) * 160 + ni * 16 + lr] = f2bf(sl[ni][r]);
#pragma unroll
        for (int r = 0; r < 4; r++) PB[(mi * 16 + rq + r) * 160 + 144 + lr] = 0;
        __syncthreads();  // S3: P ready

        // ---- O_h band = P[band] @ V (K=160 over 5 steps, 2 d-tiles) ----
        floatx4 o0 = (floatx4){0.f, 0.f, 0.f, 0.f};
        floatx4 o1 = (floatx4){0.f, 0.f, 0.f, 0.f};
#pragma unroll
        for (int kt = 0; kt < 5; kt++) {
            const bf16x8 pa = *(const bf16x8*)&PB[arow * 160 + kt * 32 + kq];
            const bf16x8 v0 = *(const bf16x8*)&vT[lr * 160 + kt * 32 + kq];
            const bf16x8 v1 = *(const bf16x8*)&vT[(16 + lr) * 160 + kt * 32 + kq];
            o0 = __builtin_amdgcn_mfma_f32_16x16x32_bf16(pa, v0, o0, 0, 0, 0);
            o1 = __builtin_amdgcn_mfma_f32_16x16x32_bf16(pa, v1, o1, 0, 0, 0);
        }
        __syncthreads();  // S4: P reads done before OB overlays P

        // ---- O_h -> LDS [144][32] bf16 (A-layout source for proj) ----
#pragma unroll
        for (int r = 0; r < 4; r++) {
            const int row = mi * 16 + rq + r;
            OB[row * 32 + lr]      = f2bf(o0[r]);
            OB[row * 32 + 16 + lr] = f2bf(o1[r]);
        }
        __syncthreads();  // S5: OB ready

        // ---- proj partial: oacc[nj] += O_h @ projw[:, h*32:+32]^T ----
        const bf16x8 pa = *(const bf16x8*)&OB[arow * 32 + kq];
#pragma unroll
        for (int nj = 0; nj < 16; nj++) {
            const bf16x8 pb = *(const bf16x8*)(projw + (size_t)(nj * 16 + lr) * 256 + h * 32 + kq);
            oacc[nj] = __builtin_amdgcn_mfma_f32_16x16x32_bf16(pa, pb, oacc[nj], 0, 0, 0);
        }
        __syncthreads();  // S6: OB reads done before next head's writes
    }

    // ---- epilogue: out[b*144+row][n] = oacc + proj_b (fp32) ----
#pragma unroll
    for (int nj = 0; nj < 16; nj++) {
        const float pbias = projb[nj * 16 + lr];
#pragma unroll
        for (int r = 0; r < 4; r++) {
            const int row = mi * 16 + rq + r;
            out[((size_t)(b * 144 + row)) * 256 + nj * 16 + lr] = oacc[nj][r] + pbias;
        }
    }
}

// ---------------------------------------------------------------------------
extern "C" void kernel_launch(void* const* d_in, const int* in_sizes, int n_in,
                              void* d_out, int out_size, void* d_ws, size_t ws_size,
                              hipStream_t stream) {
    const float* x      = (const float*)d_in[0];
    const float* mask   = (const float*)d_in[1];
    const float* qkv_w  = (const float*)d_in[2];
    const float* qkv_b  = (const float*)d_in[3];
    const float* proj_w = (const float*)d_in[4];
    const float* proj_b = (const float*)d_in[5];
    const float* fc1_w  = (const float*)d_in[6];
    const float* fc1_b  = (const float*)d_in[7];
    const float* fc2_w  = (const float*)d_in[8];
    const float* fc2_b  = (const float*)d_in[9];
    const float* lsc    = (const float*)d_in[10];
    float* out = (float*)d_out;

    float* bias_ws   = (float*)d_ws;                       // 165888 fp32 = 663 KB
    uint16_t* wqkv   = (uint16_t*)(bias_ws + 165888);      // 196608 bf16 = 393 KB
    uint16_t* wproj  = wqkv + 196608;                      // 65536 bf16 = 131 KB

    cvtw_kernel<<<768, 256, 0, stream>>>(qkv_w, proj_w, wqkv, wproj);
    rbias_kernel<<<81, 256, 0, stream>>>(fc1_w, fc1_b, fc2_w, fc2_b, bias_ws);
    fused_kernel<<<1024, 576, 0, stream>>>(x, mask, wqkv, qkv_b, wproj, proj_b,
                                           bias_ws, lsc, out);
}